// Round 3
// baseline (608.975 us; speedup 1.0000x reference)
//
#include <hip/hip_runtime.h>
#include <stdint.h>

#define MT   30      // top-M candidates
#define KNB  20      // K+1 neighbors
#define DD   512     // descriptor dim
#define XROW 516     // padded LDS row stride (floats)
#define NTILES 120   // upper-triangle 2x2 tiles of 15x15

extern "C" __global__ void __launch_bounds__(256)
mdesc_kernel(const float* __restrict__ X, const float* __restrict__ Q,
             const int* __restrict__ ranks, float* __restrict__ out, int B)
{
    __shared__ alignas(16) float XtS[MT][XROW];
    __shared__ alignas(16) float QS[DD];
    __shared__ double simS[MT][MT + 1];
    __shared__ double simPart[NTILES][4];
    __shared__ double qdotPart[MT][8];
    __shared__ double qdotS[MT];
    __shared__ float  MwS[MT][MT];
    __shared__ double scoreS[MT];
    __shared__ int    orderS[MT];
    __shared__ int    rtS[MT];

    const int b = blockIdx.x;
    const int tid = threadIdx.x;

    if (tid < MT) rtS[tid] = ranks[(size_t)tid * B + b];   // int32 per harness doc
    for (int i = tid; i < MT * MT; i += 256) (&MwS[0][0])[i] = 0.0f;
    __syncthreads();

    // ---- gather Xt rows (coalesced float4) + Q ----
    for (int i = tid; i < MT * (DD / 4); i += 256) {
        int row = i >> 7;
        int c = (i & 127) << 2;
        float4 v = *(const float4*)(X + (size_t)rtS[row] * DD + c);
        *(float4*)(&XtS[row][c]) = v;
    }
    if (tid < DD / 4) {
        float4 v = *(const float4*)(Q + (size_t)b * DD + (tid << 2));
        *(float4*)(&QS[tid << 2]) = v;
    }
    __syncthreads();

    // ---- sim = Xt·Xt^T in f64, upper-triangle 2x2 tiles, 2 d-halves ----
    double a00 = 0.0, a01 = 0.0, a10 = 0.0, a11 = 0.0;
    int i0 = 0, i1 = 0, j0 = 0, j1 = 0, tile = 0;
    const bool simActive = (tid < 2 * NTILES);
    const int half = tid & 1;
    if (simActive) {
        tile = tid >> 1;
        int I = 0, rem = tile;
        while (rem >= 15 - I) { rem -= 15 - I; ++I; }
        int J = I + rem;
        i0 = 2 * I; i1 = i0 + 1; j0 = 2 * J; j1 = j0 + 1;
        const int dbase = half * 256;
        for (int d = dbase; d < dbase + 256; d += 4) {
            float4 va0 = *(const float4*)&XtS[i0][d];
            float4 va1 = *(const float4*)&XtS[i1][d];
            float4 vb0 = *(const float4*)&XtS[j0][d];
            float4 vb1 = *(const float4*)&XtS[j1][d];
            const float* A0 = (const float*)&va0;
            const float* A1 = (const float*)&va1;
            const float* B0 = (const float*)&vb0;
            const float* B1 = (const float*)&vb1;
            #pragma unroll
            for (int c = 0; c < 4; ++c) {
                double x0 = (double)A0[c], x1 = (double)A1[c];
                double y0 = (double)B0[c], y1 = (double)B1[c];
                a00 = fma(x0, y0, a00);
                a01 = fma(x0, y1, a01);
                a10 = fma(x1, y0, a10);
                a11 = fma(x1, y1, a11);
            }
        }
        if (half) {
            simPart[tile][0] = a00; simPart[tile][1] = a01;
            simPart[tile][2] = a10; simPart[tile][3] = a11;
        }
    }
    __syncthreads();
    if (simActive && half == 0) {
        a00 += simPart[tile][0]; a01 += simPart[tile][1];
        a10 += simPart[tile][2]; a11 += simPart[tile][3];
        simS[i0][j0] = a00; simS[j0][i0] = a00;
        simS[i0][j1] = a01; simS[j1][i0] = a01;
        simS[i1][j0] = a10; simS[j0][i1] = a10;
        simS[i1][j1] = a11; simS[j1][i1] = a11;
    }
    // ---- qdots = Q·Xt[m] in f64 (8 lanes per row) ----
    if (tid < 240) {
        int m = tid >> 3, s = tid & 7;
        double acc = 0.0;
        const int dbase = s * 64;
        for (int d = dbase; d < dbase + 64; d += 4) {
            float4 q = *(const float4*)&QS[d];
            float4 x = *(const float4*)&XtS[m][d];
            const float* qq = (const float*)&q;
            const float* xx = (const float*)&x;
            #pragma unroll
            for (int c = 0; c < 4; ++c)
                acc = fma((double)qq[c], (double)xx[c], acc);
        }
        qdotPart[m][s] = acc;
    }
    __syncthreads();
    if (tid < MT) {
        double acc = 0.0;
        #pragma unroll
        for (int s = 0; s < 8; ++s) acc += qdotPart[tid][s];
        qdotS[tid] = acc;
    }
    __syncthreads();

    // ---- per-row top-20 selection (desc value, ties -> lowest index), weights, score ----
    if (tid < MT) {
        const int m = tid;
        unsigned used = 0;
        double Wsum = 0.0, sAcc = 0.0;
        for (int k = 0; k < KNB; ++k) {
            double best = -1.0e300; int bj = 0;
            for (int j = 0; j < MT; ++j) {
                if (used & (1u << j)) continue;
                double v = simS[m][j];
                if (v > best) { best = v; bj = j; }
            }
            used |= (1u << bj);
            double w = (k == 0) ? 1.0 : best * 0.15;
            Wsum += w;
            sAcc = fma(w, qdotS[bj], sAcc);
            MwS[m][bj] = (float)w;
        }
        scoreS[m] = sAcc / Wsum;
        float inv = (float)(1.0 / Wsum);
        for (int j = 0; j < MT; ++j)
            if (used & (1u << j)) MwS[m][j] *= inv;
    }
    __syncthreads();

    // ---- stable rank of scores (desc, ties -> lowest index) ----
    if (tid < MT) {
        double mysc = scoreS[tid];
        int pos = 0;
        for (int j = 0; j < MT; ++j) {
            double v = scoreS[j];
            if (v > mysc || (v == mysc && j < tid)) ++pos;
        }
        orderS[pos] = tid;
    }
    __syncthreads();

    const size_t sec = (size_t)B * MT;
    if (tid < MT) {
        int r = tid;
        int src = orderS[r];
        out[(size_t)b * MT + r]            = (float)rtS[src];    // rerank (f32!)
        out[sec + (size_t)b * MT + tid]    = (float)scoreS[tid]; // scores (orig order)
        out[2 * sec + (size_t)b * MT + r]  = (float)src;         // order
    }

    // ---- x_dba = Mw(30x30) * Xt(30x512) in f32, write f32 ----
    const size_t xbase = 3 * sec;
    for (int i = tid; i < MT * (DD / 4); i += 256) {
        int m = i >> 7;
        int c = (i & 127) << 2;
        float acc0 = 0.f, acc1 = 0.f, acc2 = 0.f, acc3 = 0.f;
        for (int j = 0; j < MT; ++j) {
            float wj = MwS[m][j];
            if (wj != 0.0f) {
                float4 v = *(const float4*)&XtS[j][c];
                acc0 = fmaf(wj, v.x, acc0);
                acc1 = fmaf(wj, v.y, acc1);
                acc2 = fmaf(wj, v.z, acc2);
                acc3 = fmaf(wj, v.w, acc3);
            }
        }
        float4 o = make_float4(acc0, acc1, acc2, acc3);
        *(float4*)(out + xbase + ((size_t)b * MT + m) * DD + c) = o;
    }
}

extern "C" void kernel_launch(void* const* d_in, const int* in_sizes, int n_in,
                              void* d_out, int out_size, void* d_ws, size_t ws_size,
                              hipStream_t stream)
{
    const float* X = (const float*)d_in[0];
    const float* Q = (const float*)d_in[1];
    const int* ranks = (const int*)d_in[2];
    const int B = in_sizes[1] / DD;   // 4096
    mdesc_kernel<<<dim3(B), dim3(256), 0, stream>>>(X, Q, ranks, (float*)d_out, B);
}